// Round 1
// baseline (598.641 us; speedup 1.0000x reference)
//
#include <hip/hip_runtime.h>
#include <hip/hip_bf16.h>

#define WDIM 256
#define HEADS 8
#define HD 32
#define NTOK 49
#define NWIN 64
#define NBATCH 2048
#define QK_SCALE 0.17677669529663687f  // 32^-0.5

typedef float f32x4 __attribute__((ext_vector_type(4)));
typedef short s16x8 __attribute__((ext_vector_type(8)));
typedef unsigned short u16;

// ---- LDS layout (ushort element offsets). All row strides are 16B multiples. ----
#define XS 0
#define XS_STR 264            // 64 rows x 264 (bank stride 4 -> 2-way, free)
#define QS 16896              // 49 rows x 40
#define QK_STR 40
#define KS 18856              // 49 rows x 40
#define VT 20816              // 32 rows x 72 (V transposed: [d][m])
#define VT_STR 72
#define PS 23120              // 64 rows x 72
#define PS_STR 72
#define OUTS 27728            // 49 rows x 264
#define OUT_STR 264
#define SMEM_ELEMS 40664      // 81,328 bytes -> 2 blocks/CU

__device__ __forceinline__ u16 f2bf(float f) {
    unsigned u = __builtin_bit_cast(unsigned, f);
    u = (u + 0x7fffu + ((u >> 16) & 1u)) >> 16;
    return (u16)u;
}

__global__ void prep_weights(const float* __restrict__ qkv_w, const float* __restrict__ proj_w,
                             u16* __restrict__ qkvw, u16* __restrict__ projw) {
    int i = blockIdx.x * 256 + threadIdx.x;
    if (i < 196608) qkvw[i] = f2bf(qkv_w[i]);
    if (i < 65536)  projw[i] = f2bf(proj_w[i]);
}

__global__ void prep_bias(const int* __restrict__ rel_index, const float* __restrict__ bias_table,
                          float* __restrict__ biasf) {
    int i = blockIdx.x * 256 + threadIdx.x;
    if (i < NTOK * NTOK) {
        int r = rel_index[i];
#pragma unroll
        for (int h = 0; h < HEADS; ++h)
            biasf[h * (NTOK * NTOK) + i] = bias_table[r * HEADS + h];
    }
}

__global__ __launch_bounds__(256, 2)
void swin_attn_kernel(const float* __restrict__ x,
                      const float* __restrict__ mask,
                      const float* __restrict__ qkv_b,
                      const float* __restrict__ proj_b,
                      const u16* __restrict__ qkvw,
                      const u16* __restrict__ projw,
                      const float* __restrict__ biasf,
                      float* __restrict__ out) {
    __shared__ __align__(16) u16 sm[SMEM_ELEMS];
    const int b = blockIdx.x;
    const int tid = threadIdx.x;
    const int wv = tid >> 6;          // wave 0..3
    const int lane = tid & 63;
    const int g = lane >> 4;          // k-group 0..3
    const int c = lane & 15;          // row/col within 16-tile
    const int wi = b & (NWIN - 1);
    const int RB = wv * 16;           // this wave's output row-tile base
    const float* xw = x + (size_t)b * (NTOK * WDIM);

    // ---- Phase A: stage x window into LDS as bf16, zero-pad rows 49..63 ----
    for (int i = tid; i < NTOK * (WDIM / 4); i += 256) {
        int row = i >> 6, q4 = i & 63;
        float4 v = ((const float4*)xw)[i];
        ushort4 s;
        s.x = f2bf(v.x); s.y = f2bf(v.y); s.z = f2bf(v.z); s.w = f2bf(v.w);
        *(ushort4*)&sm[XS + row * XS_STR + q4 * 4] = s;
    }
    for (int i = tid; i < 15 * (XS_STR / 4); i += 256) {
        *(ushort4*)&sm[XS + 49 * XS_STR + i * 4] = make_ushort4(0, 0, 0, 0);
    }
    __syncthreads();

    // ---- Per-head loop ----
    for (int h = 0; h < HEADS; ++h) {
        // Phase B: QKV projection for this head. Wave computes its 16-row tile
        // over 6 col-tiles: t=0,1 -> Q cols, 2,3 -> K cols, 4,5 -> V cols.
        f32x4 acc[6];
#pragma unroll
        for (int t = 0; t < 6; ++t) acc[t] = f32x4{0.f, 0.f, 0.f, 0.f};
        int wrow[6];
#pragma unroll
        for (int t = 0; t < 6; ++t)
            wrow[t] = (t >> 1) * 256 + h * 32 + (t & 1) * 16 + c;
#pragma unroll
        for (int ks = 0; ks < 8; ++ks) {
            s16x8 a = *(const s16x8*)&sm[XS + (RB + c) * XS_STR + ks * 32 + g * 8];
#pragma unroll
            for (int t = 0; t < 6; ++t) {
                s16x8 bb = *(const s16x8*)&qkvw[(size_t)wrow[t] * 256 + ks * 32 + g * 8];
                acc[t] = __builtin_amdgcn_mfma_f32_16x16x32_bf16(a, bb, acc[t], 0, 0, 0);
            }
        }
#pragma unroll
        for (int t = 0; t < 6; ++t) {
            int sel = t >> 1;
            int col32 = (t & 1) * 16 + c;
            float bb = qkv_b[wrow[t]];
#pragma unroll
            for (int j = 0; j < 4; ++j) {
                int row = RB + g * 4 + j;
                float v = acc[t][j] + bb;
                if (sel == 0)      { if (row < NTOK) sm[QS + row * QK_STR + col32] = f2bf(v * QK_SCALE); }
                else if (sel == 1) { if (row < NTOK) sm[KS + row * QK_STR + col32] = f2bf(v); }
                else               { sm[VT + col32 * VT_STR + row] = f2bf(v); }  // V transposed, all rows (finite)
            }
        }
        __syncthreads();

        // Phase C: logits = QK^T (+bias+mask), wave-parallel softmax, P -> LDS bf16
        s16x8 aq = *(const s16x8*)&sm[QS + min(RB + c, 48) * QK_STR + g * 8];
        f32x4 p[4];
#pragma unroll
        for (int t = 0; t < 4; ++t) {
            s16x8 bk = *(const s16x8*)&sm[KS + min(t * 16 + c, 48) * QK_STR + g * 8];
            f32x4 z = {0.f, 0.f, 0.f, 0.f};
            p[t] = __builtin_amdgcn_mfma_f32_16x16x32_bf16(aq, bk, z, 0, 0, 0);
        }
        float lv[4][4];
        float mx[4] = {-1e30f, -1e30f, -1e30f, -1e30f};
#pragma unroll
        for (int t = 0; t < 4; ++t) {
            int col = t * 16 + c;
#pragma unroll
            for (int j = 0; j < 4; ++j) {
                float v;
                if (col < NTOK) {
                    int rr = min(RB + g * 4 + j, 48);
                    v = p[t][j] + biasf[(h * NTOK + rr) * NTOK + col]
                                + mask[((size_t)wi * NTOK + rr) * NTOK + col];
                } else {
                    v = -1e30f;
                }
                lv[t][j] = v;
                mx[j] = fmaxf(mx[j], v);
            }
        }
#pragma unroll
        for (int j = 0; j < 4; ++j) {
            mx[j] = fmaxf(mx[j], __shfl_xor(mx[j], 1));
            mx[j] = fmaxf(mx[j], __shfl_xor(mx[j], 2));
            mx[j] = fmaxf(mx[j], __shfl_xor(mx[j], 4));
            mx[j] = fmaxf(mx[j], __shfl_xor(mx[j], 8));
        }
        float sum[4] = {0.f, 0.f, 0.f, 0.f};
#pragma unroll
        for (int t = 0; t < 4; ++t)
#pragma unroll
            for (int j = 0; j < 4; ++j) {
                float e = __expf(lv[t][j] - mx[j]);
                lv[t][j] = e;
                sum[j] += e;
            }
#pragma unroll
        for (int j = 0; j < 4; ++j) {
            sum[j] += __shfl_xor(sum[j], 1);
            sum[j] += __shfl_xor(sum[j], 2);
            sum[j] += __shfl_xor(sum[j], 4);
            sum[j] += __shfl_xor(sum[j], 8);
            sum[j] = 1.0f / sum[j];
        }
#pragma unroll
        for (int t = 0; t < 4; ++t)
#pragma unroll
            for (int j = 0; j < 4; ++j) {
                int row = RB + g * 4 + j;
                sm[PS + row * PS_STR + t * 16 + c] = f2bf(lv[t][j] * sum[j]);
            }
        __syncthreads();

        // Phase D: out_head = P @ V  (B-operand = Vt[d][m])
        f32x4 o[2] = {{0.f, 0.f, 0.f, 0.f}, {0.f, 0.f, 0.f, 0.f}};
#pragma unroll
        for (int ks = 0; ks < 2; ++ks) {
            s16x8 ap = *(const s16x8*)&sm[PS + (RB + c) * PS_STR + ks * 32 + g * 8];
#pragma unroll
            for (int t = 0; t < 2; ++t) {
                s16x8 bv = *(const s16x8*)&sm[VT + (t * 16 + c) * VT_STR + ks * 32 + g * 8];
                o[t] = __builtin_amdgcn_mfma_f32_16x16x32_bf16(ap, bv, o[t], 0, 0, 0);
            }
        }
#pragma unroll
        for (int t = 0; t < 2; ++t)
#pragma unroll
            for (int j = 0; j < 4; ++j) {
                int row = RB + g * 4 + j;
                if (row < NTOK)
                    sm[OUTS + row * OUT_STR + h * 32 + t * 16 + c] = f2bf(o[t][j]);
            }
        __syncthreads();
    }

    // ---- Phase E: final projection (49x256 @ 256x256) + bias, write f32 ----
    f32x4 acc4[16];
#pragma unroll
    for (int t = 0; t < 16; ++t) acc4[t] = f32x4{0.f, 0.f, 0.f, 0.f};
    for (int ks = 0; ks < 8; ++ks) {
        s16x8 ao = *(const s16x8*)&sm[OUTS + min(RB + c, 48) * OUT_STR + ks * 32 + g * 8];
#pragma unroll
        for (int t = 0; t < 16; ++t) {
            s16x8 bp = *(const s16x8*)&projw[(t * 16 + c) * 256 + ks * 32 + g * 8];
            acc4[t] = __builtin_amdgcn_mfma_f32_16x16x32_bf16(ao, bp, acc4[t], 0, 0, 0);
        }
    }
    float* ob = out + (size_t)b * (NTOK * WDIM);
#pragma unroll
    for (int t = 0; t < 16; ++t) {
        float pb = proj_b[t * 16 + c];
#pragma unroll
        for (int j = 0; j < 4; ++j) {
            int row = RB + g * 4 + j;
            if (row < NTOK) ob[row * 256 + t * 16 + c] = acc4[t][j] + pb;
        }
    }
}

extern "C" void kernel_launch(void* const* d_in, const int* in_sizes, int n_in,
                              void* d_out, int out_size, void* d_ws, size_t ws_size,
                              hipStream_t stream) {
    const float* x          = (const float*)d_in[0];
    const float* mask       = (const float*)d_in[1];
    const float* qkv_w      = (const float*)d_in[2];
    const float* qkv_b      = (const float*)d_in[3];
    const float* bias_table = (const float*)d_in[4];
    const float* proj_w     = (const float*)d_in[5];
    const float* proj_b     = (const float*)d_in[6];
    const int*   rel_index  = (const int*)d_in[7];

    u16*   qkvw  = (u16*)d_ws;                          // 196608 bf16 = 393,216 B
    u16*   projw = qkvw + 196608;                       // 65536 bf16 = 131,072 B
    float* biasf = (float*)((char*)d_ws + 524288);      // 8*49*49 f32 = 76,832 B

    prep_weights<<<768, 256, 0, stream>>>(qkv_w, proj_w, qkvw, projw);
    prep_bias<<<10, 256, 0, stream>>>(rel_index, bias_table, biasf);
    swin_attn_kernel<<<NBATCH, 256, 0, stream>>>(x, mask, qkv_b, proj_b, qkvw, projw, biasf,
                                                 (float*)d_out);
}

// Round 2
// 166.235 us; speedup vs baseline: 3.6012x; 3.6012x over previous
//
#include <hip/hip_runtime.h>

typedef float f32x4 __attribute__((ext_vector_type(4)));
typedef short s16x8 __attribute__((ext_vector_type(8)));
typedef unsigned short u16;

#define QK_SCALE 0.17677669529663687f  // 32^-0.5

__device__ __forceinline__ u16 f2bf(float f) {
    unsigned u = __builtin_bit_cast(unsigned, f);
    u = (u + 0x7fffu + ((u >> 16) & 1u)) >> 16;
    return (u16)u;
}

// ---- workspace byte offsets ----
// qkvwC : 196608 bf16 = 393216 B   [h8][t6][ks8][lane64][e8]
// projwC:  65536 bf16 = 131072 B   [nt16][ks8][lane64][e8]
// biasC :  32768 f32  = 131072 B   [h8][tile16][lane64][j4]  (k>=49 -> -1e30 folded in)
// maskC : 262144 f32  = 1048576 B  [wi64][tile16][lane64][j4]
#define WS_PROJW 393216
#define WS_BIASC 524288
#define WS_MASKC 655360

__global__ void prep(const float* __restrict__ qkv_w, const float* __restrict__ proj_w,
                     const float* __restrict__ bias_table, const int* __restrict__ rel_index,
                     const float* __restrict__ mask,
                     u16* __restrict__ qkvwC, u16* __restrict__ projwC,
                     float* __restrict__ biasC, float* __restrict__ maskC) {
    int i = blockIdx.x * 256 + threadIdx.x;
    if (i < 196608) {                       // qkv weights -> fragment order
        int e = i & 7, lane = (i >> 3) & 63, ks = (i >> 9) & 7, i2 = i >> 12;
        int t = i2 % 6, h = i2 / 6;
        int c = lane & 15, g = lane >> 4;
        int wrow = (t >> 1) * 256 + h * 32 + (t & 1) * 16 + c;
        qkvwC[i] = f2bf(qkv_w[wrow * 256 + ks * 32 + g * 8 + e]);
    }
    if (i < 65536) {                        // proj weights -> fragment order
        int e = i & 7, lane = (i >> 3) & 63, ks = (i >> 9) & 7, nt = (i >> 12) & 15;
        int c = lane & 15, g = lane >> 4;
        projwC[i] = f2bf(proj_w[(nt * 16 + c) * 256 + ks * 32 + g * 8 + e]);
    }
    if (i < 32768) {                        // rel-pos bias -> C-fragment order
        int j = i & 3, lane = (i >> 2) & 63, tile = (i >> 8) & 15, h = i >> 12;
        int mt = tile >> 2, nt = tile & 3, g = lane >> 4, c = lane & 15;
        int q = mt * 16 + g * 4 + j, k = nt * 16 + c;
        float v;
        if (k < 49) v = (q < 49) ? bias_table[rel_index[q * 49 + k] * 8 + h] : 0.f;
        else        v = -1e30f;             // pad-column mask folded in
        biasC[i] = v;
    }
    if (i < 262144) {                       // shift mask -> C-fragment order
        int j = i & 3, lane = (i >> 2) & 63, tile = (i >> 8) & 15, wi = i >> 12;
        int mt = tile >> 2, nt = tile & 3, g = lane >> 4, c = lane & 15;
        int q = mt * 16 + g * 4 + j, k = nt * 16 + c;
        maskC[i] = (q < 49 && k < 49) ? mask[wi * 2401 + q * 49 + k] : 0.f;
    }
}

// ---- LDS layout (ushort offsets), total 38416 ushorts = 76832 B -> 2 blocks/CU ----
// XS   : 0,               stride 264, 50 rows (row 49 zeroed)
// wave scratch at PW = 13200 + wv*6304:
//   Q  : PW,        stride 40, 50 rows (2000)
//   K  : PW+2000,   stride 40, 50 rows (2000)
//   VT : PW+4000,   stride 72, 32 rows (2304)
//   P  : PW (overlaps dead Q+K), stride 72, 50 rows (3600 <= 4000)
// OUTS : 13200 (overlaps all wave scratch after barrier), stride 264, 49 rows
__global__ __launch_bounds__(256, 2)
void swin_attn(const float* __restrict__ x,
               const float* __restrict__ qkv_b,
               const float* __restrict__ proj_b,
               const u16* __restrict__ qkvwC,
               const u16* __restrict__ projwC,
               const float* __restrict__ biasC,
               const float* __restrict__ maskC,
               float* __restrict__ out) {
    __shared__ __align__(16) u16 sm[38416];
    const int b = blockIdx.x, tid = threadIdx.x;
    const int wv = tid >> 6, lane = tid & 63, g = lane >> 4, c = lane & 15;
    const int wi = b & 63;
    const int PW = 13200 + wv * 6304;
    const float* xw = x + (size_t)b * 12544;

    // stage x window (bf16) rows 0..48, zero row 49
    for (int i = tid; i < 49 * 64; i += 256) {
        int row = i >> 6, q4 = i & 63;
        float4 v = ((const float4*)xw)[i];
        ushort4 s;
        s.x = f2bf(v.x); s.y = f2bf(v.y); s.z = f2bf(v.z); s.w = f2bf(v.w);
        *(ushort4*)&sm[row * 264 + q4 * 4] = s;
    }
    if (tid < 64) *(ushort4*)&sm[49 * 264 + tid * 4] = make_ushort4(0, 0, 0, 0);
    __syncthreads();

    float oreg[2][4][2][4];

#pragma unroll
    for (int hl = 0; hl < 2; ++hl) {
        const int hh = wv * 2 + hl;

        // ---- QKV projection: this wave's 2 heads, all 64 rows ----
        f32x4 acc[4][6];
#pragma unroll
        for (int mt = 0; mt < 4; ++mt)
#pragma unroll
            for (int t = 0; t < 6; ++t) acc[mt][t] = f32x4{0.f, 0.f, 0.f, 0.f};
#pragma unroll
        for (int ks = 0; ks < 8; ++ks) {
            s16x8 a[4];
#pragma unroll
            for (int mt = 0; mt < 4; ++mt) {
                int row = mt * 16 + c; row = row > 49 ? 49 : row;
                a[mt] = *(const s16x8*)&sm[row * 264 + ks * 32 + g * 8];
            }
#pragma unroll
            for (int t = 0; t < 6; ++t) {
                s16x8 bb = *(const s16x8*)&qkvwC[(((hh * 6 + t) * 8 + ks) * 64 + lane) * 8];
#pragma unroll
                for (int mt = 0; mt < 4; ++mt)
                    acc[mt][t] = __builtin_amdgcn_mfma_f32_16x16x32_bf16(a[mt], bb, acc[mt][t], 0, 0, 0);
            }
        }
        // distribute to wave-private Q / K / V^T
#pragma unroll
        for (int t = 0; t < 6; ++t) {
            float bv = qkv_b[(t >> 1) * 256 + hh * 32 + (t & 1) * 16 + c];
#pragma unroll
            for (int mt = 0; mt < 4; ++mt)
#pragma unroll
                for (int j = 0; j < 4; ++j) {
                    int row = mt * 16 + g * 4 + j;
                    float v = acc[mt][t][j] + bv;
                    if (t < 2)      { if (row < 50) sm[PW + row * 40 + (t & 1) * 16 + c] = f2bf(v * QK_SCALE); }
                    else if (t < 4) { if (row < 50) sm[PW + 2000 + row * 40 + (t & 1) * 16 + c] = f2bf(v); }
                    else            { sm[PW + 4000 + ((t & 1) * 16 + c) * 72 + row] = f2bf(v); }
                }
        }

        // ---- QK^T + bias + mask, wave-local softmax ----
        s16x8 aq[4], bk[4];
#pragma unroll
        for (int mt = 0; mt < 4; ++mt) {
            int row = mt * 16 + c; row = row > 49 ? 49 : row;
            aq[mt] = *(const s16x8*)&sm[PW + row * 40 + g * 8];
        }
#pragma unroll
        for (int nt = 0; nt < 4; ++nt) {
            int row = nt * 16 + c; row = row > 49 ? 49 : row;
            bk[nt] = *(const s16x8*)&sm[PW + 2000 + row * 40 + g * 8];
        }
        float lv[4][4][4], mx[4][4];
#pragma unroll
        for (int mt = 0; mt < 4; ++mt)
#pragma unroll
            for (int j = 0; j < 4; ++j) mx[mt][j] = -1e30f;
#pragma unroll
        for (int mt = 0; mt < 4; ++mt)
#pragma unroll
            for (int nt = 0; nt < 4; ++nt) {
                f32x4 z = {0.f, 0.f, 0.f, 0.f};
                f32x4 s4 = __builtin_amdgcn_mfma_f32_16x16x32_bf16(aq[mt], bk[nt], z, 0, 0, 0);
                f32x4 bb = *(const f32x4*)&biasC[((hh * 16 + mt * 4 + nt) * 64 + lane) * 4];
                f32x4 mm = *(const f32x4*)&maskC[((wi * 16 + mt * 4 + nt) * 64 + lane) * 4];
#pragma unroll
                for (int j = 0; j < 4; ++j) {
                    float v = s4[j] + bb[j] + mm[j];
                    lv[mt][nt][j] = v;
                    mx[mt][j] = fmaxf(mx[mt][j], v);
                }
            }
#pragma unroll
        for (int mt = 0; mt < 4; ++mt)
#pragma unroll
            for (int j = 0; j < 4; ++j) {
                float m = mx[mt][j];
                m = fmaxf(m, __shfl_xor(m, 1));
                m = fmaxf(m, __shfl_xor(m, 2));
                m = fmaxf(m, __shfl_xor(m, 4));
                m = fmaxf(m, __shfl_xor(m, 8));
                mx[mt][j] = m;
            }
        float sums[4][4];
#pragma unroll
        for (int mt = 0; mt < 4; ++mt)
#pragma unroll
            for (int j = 0; j < 4; ++j) sums[mt][j] = 0.f;
#pragma unroll
        for (int mt = 0; mt < 4; ++mt)
#pragma unroll
            for (int nt = 0; nt < 4; ++nt)
#pragma unroll
                for (int j = 0; j < 4; ++j) {
                    float e = __expf(lv[mt][nt][j] - mx[mt][j]);
                    lv[mt][nt][j] = e;
                    sums[mt][j] += e;
                }
#pragma unroll
        for (int mt = 0; mt < 4; ++mt)
#pragma unroll
            for (int j = 0; j < 4; ++j) {
                float s = sums[mt][j];
                s += __shfl_xor(s, 1);
                s += __shfl_xor(s, 2);
                s += __shfl_xor(s, 4);
                s += __shfl_xor(s, 8);
                sums[mt][j] = 1.0f / s;     // inv-sum; normalization deferred to PV output
            }
        // write unnormalized P (overlaps dead Q+K)
#pragma unroll
        for (int mt = 0; mt < 4; ++mt)
#pragma unroll
            for (int nt = 0; nt < 4; ++nt)
#pragma unroll
                for (int j = 0; j < 4; ++j) {
                    int row = mt * 16 + g * 4 + j;
                    if (row < 50) sm[PW + row * 72 + nt * 16 + c] = f2bf(lv[mt][nt][j]);
                }

        // ---- PV ----
        f32x4 o[4][2];
#pragma unroll
        for (int mt = 0; mt < 4; ++mt)
#pragma unroll
            for (int n2 = 0; n2 < 2; ++n2) o[mt][n2] = f32x4{0.f, 0.f, 0.f, 0.f};
#pragma unroll
        for (int ks2 = 0; ks2 < 2; ++ks2) {
            s16x8 ap[4], bv2[2];
#pragma unroll
            for (int mt = 0; mt < 4; ++mt) {
                int row = mt * 16 + c; row = row > 49 ? 49 : row;
                ap[mt] = *(const s16x8*)&sm[PW + row * 72 + ks2 * 32 + g * 8];
            }
#pragma unroll
            for (int n2 = 0; n2 < 2; ++n2)
                bv2[n2] = *(const s16x8*)&sm[PW + 4000 + (n2 * 16 + c) * 72 + ks2 * 32 + g * 8];
#pragma unroll
            for (int mt = 0; mt < 4; ++mt)
#pragma unroll
                for (int n2 = 0; n2 < 2; ++n2)
                    o[mt][n2] = __builtin_amdgcn_mfma_f32_16x16x32_bf16(ap[mt], bv2[n2], o[mt][n2], 0, 0, 0);
        }
#pragma unroll
        for (int mt = 0; mt < 4; ++mt)
#pragma unroll
            for (int n2 = 0; n2 < 2; ++n2)
#pragma unroll
                for (int j = 0; j < 4; ++j)
                    oreg[hl][mt][n2][j] = o[mt][n2][j] * sums[mt][j];
    }

    __syncthreads();   // all waves done with private scratch
    // stage head outputs (bf16) into OUTS (overlaps wave scratch)
#pragma unroll
    for (int hl = 0; hl < 2; ++hl)
#pragma unroll
        for (int mt = 0; mt < 4; ++mt)
#pragma unroll
            for (int n2 = 0; n2 < 2; ++n2)
#pragma unroll
                for (int j = 0; j < 4; ++j) {
                    int row = mt * 16 + g * 4 + j;
                    if (row < 49)
                        sm[13200 + row * 264 + (wv * 2 + hl) * 32 + n2 * 16 + c] = f2bf(oreg[hl][mt][n2][j]);
                }
    __syncthreads();

    // ---- output projection: wave wv covers cols [wv*64, wv*64+64) ----
    f32x4 pacc[4][4];
#pragma unroll
    for (int mt = 0; mt < 4; ++mt)
#pragma unroll
        for (int n = 0; n < 4; ++n) pacc[mt][n] = f32x4{0.f, 0.f, 0.f, 0.f};
#pragma unroll
    for (int ks = 0; ks < 8; ++ks) {
        s16x8 ao[4];
#pragma unroll
        for (int mt = 0; mt < 4; ++mt) {
            int row = mt * 16 + c; row = row > 48 ? 48 : row;
            ao[mt] = *(const s16x8*)&sm[13200 + row * 264 + ks * 32 + g * 8];
        }
#pragma unroll
        for (int n = 0; n < 4; ++n) {
            s16x8 bp = *(const s16x8*)&projwC[(((wv * 4 + n) * 8 + ks) * 64 + lane) * 8];
#pragma unroll
            for (int mt = 0; mt < 4; ++mt)
                pacc[mt][n] = __builtin_amdgcn_mfma_f32_16x16x32_bf16(ao[mt], bp, pacc[mt][n], 0, 0, 0);
        }
    }
    float* ob = out + (size_t)b * 12544;
#pragma unroll
    for (int n = 0; n < 4; ++n) {
        int col = (wv * 4 + n) * 16 + c;
        float pb = proj_b[col];
#pragma unroll
        for (int mt = 0; mt < 4; ++mt)
#pragma unroll
            for (int j = 0; j < 4; ++j) {
                int row = mt * 16 + g * 4 + j;
                if (row < 49) ob[row * 256 + col] = pacc[mt][n][j] + pb;
            }
    }
}

extern "C" void kernel_launch(void* const* d_in, const int* in_sizes, int n_in,
                              void* d_out, int out_size, void* d_ws, size_t ws_size,
                              hipStream_t stream) {
    const float* x          = (const float*)d_in[0];
    const float* mask       = (const float*)d_in[1];
    const float* qkv_w      = (const float*)d_in[2];
    const float* qkv_b      = (const float*)d_in[3];
    const float* bias_table = (const float*)d_in[4];
    const float* proj_w     = (const float*)d_in[5];
    const float* proj_b     = (const float*)d_in[6];
    const int*   rel_index  = (const int*)d_in[7];

    u16*   qkvwC  = (u16*)d_ws;
    u16*   projwC = (u16*)((char*)d_ws + WS_PROJW);
    float* biasC  = (float*)((char*)d_ws + WS_BIASC);
    float* maskC  = (float*)((char*)d_ws + WS_MASKC);

    prep<<<1024, 256, 0, stream>>>(qkv_w, proj_w, bias_table, rel_index, mask,
                                   qkvwC, projwC, biasC, maskC);
    swin_attn<<<2048, 256, 0, stream>>>(x, qkv_b, proj_b, qkvwC, projwC, biasC, maskC,
                                        (float*)d_out);
}